// Round 18
// baseline (106.615 us; speedup 1.0000x reference)
//
#include <hip/hip_runtime.h>

#define NB 8
#define TE 256
#define TD 256
#define DE 512
#define QT 4

// K2 = 2*log2(e): exp2(K2*x) = e^{2x}; tanh(x) = 1 - 2/(e^{2x}+1).
#define K2SCALE 2.8853900817779268f

typedef short bf16x8 __attribute__((ext_vector_type(8)));           // 8 bf16 (4 VGPR)
typedef float f32x4 __attribute__((ext_vector_type(4)));            // MFMA acc
typedef float f32x2 __attribute__((ext_vector_type(2)));            // v_pk_*_f32 pair
typedef unsigned short u16x8 __attribute__((ext_vector_type(8)));   // 16 B staging

// round-to-nearest-even f32 -> bf16
static __device__ __forceinline__ unsigned short f2bf(float x) {
  unsigned int u = __float_as_uint(x);
  u += 0x7fffu + ((u >> 16) & 1u);
  return (unsigned short)(u >> 16);
}

// split f32 -> hi (ROUNDED bf16) + lo (rounded residual).
static __device__ __forceinline__ void split8(
    const float4& x0, const float4& x1, u16x8& h, u16x8& l) {
  float xs[8] = {x0.x, x0.y, x0.z, x0.w, x1.x, x1.y, x1.z, x1.w};
  #pragma unroll
  for (int j = 0; j < 8; ++j) {
    unsigned short hh = f2bf(xs[j]);
    float hf = __uint_as_float((unsigned int)hh << 16);
    h[j] = hh;
    l[j] = f2bf(xs[j] - hf);
  }
}

// DPP cross-lane fetch at full VALU rate (no DS, no lgkmcnt chain).
// 0xB1 = quad_perm[1,0,3,2] (xor1), 0x4E = quad_perm[2,3,0,1] (xor2),
// 0x124 = row_ror:4, 0x128 = row_ror:8 (within 16-lane row).
template <int CTRL>
static __device__ __forceinline__ float dpp_mov(float x) {
  return __int_as_float(__builtin_amdgcn_update_dpp(
      0, __float_as_int(x), CTRL, 0xf, 0xf, true));
}

// ---- convB: W [512x512] f32 -> TRANSPOSED hi/lo bf16 BT[n][k] (32x32 tiles) ----
// grid (16, 16, 2), 256 thr.  (R6-exact: chain minimum)
__global__ __launch_bounds__(256) void convB(
    const float* __restrict__ w0, unsigned short* __restrict__ h0, unsigned short* __restrict__ l0,
    const float* __restrict__ w1, unsigned short* __restrict__ h1, unsigned short* __restrict__ l1)
{
  const float* W = blockIdx.z ? w1 : w0;
  unsigned short* H = blockIdx.z ? h1 : h0;
  unsigned short* L = blockIdx.z ? l1 : l0;
  __shared__ unsigned short sh[32][33], sl[32][33];
  const int t = threadIdx.x;
  const int k0 = blockIdx.y * 32, n0 = blockIdx.x * 32;
  const int r = t >> 3, c = (t & 7) * 4;
  float4 x = *(const float4*)(W + (size_t)(k0 + r) * DE + n0 + c);
  float xs[4] = {x.x, x.y, x.z, x.w};
  #pragma unroll
  for (int j = 0; j < 4; ++j) {
    unsigned short hh = f2bf(xs[j]);
    float hf = __uint_as_float((unsigned int)hh << 16);
    sh[r][c + j] = hh;
    sl[r][c + j] = f2bf(xs[j] - hf);
  }
  __syncthreads();
  ushort4 oh, ol;
  oh.x = sh[c + 0][r]; oh.y = sh[c + 1][r]; oh.z = sh[c + 2][r]; oh.w = sh[c + 3][r];
  ol.x = sl[c + 0][r]; ol.y = sl[c + 1][r]; ol.z = sl[c + 2][r]; ol.w = sl[c + 3][r];
  *(ushort4*)(H + (size_t)(n0 + r) * DE + k0 + c) = oh;
  *(ushort4*)(L + (size_t)(n0 + r) * DE + k0 + c) = ol;
}

// ---- gemm_mfma: C = exp2(K2 * A@B), A f32 split in-register, dbuf LDS ---------
// R6-exact: BM=64 BN=64 KT=32, 256 thr (4 waves 2x2), wave-tile 32x32,
// grid (8, 32, 2) 2D decode.
__global__ __launch_bounds__(256) void gemm_mfma(
    const float* __restrict__ A0,
    const unsigned short* __restrict__ BH0, const unsigned short* __restrict__ BL0,
    float* __restrict__ C0,
    const float* __restrict__ A1,
    const unsigned short* __restrict__ BH1, const unsigned short* __restrict__ BL1,
    float* __restrict__ C1)
{
  const float*          A  = blockIdx.z ? A1  : A0;
  const unsigned short* BH = blockIdx.z ? BH1 : BH0;
  const unsigned short* BL = blockIdx.z ? BL1 : BL0;
  float*                C  = blockIdx.z ? C1  : C0;
  const int tid  = threadIdx.x;
  const int lane = tid & 63;
  const int wave = tid >> 6;
  const int wm = wave >> 1, wn = wave & 1;
  const int g = lane >> 4, r16 = lane & 15;
  const int m0 = blockIdx.y * 64, n0 = blockIdx.x * 64;
  __shared__ __align__(16) unsigned short Ah[2][64][40], Al[2][64][40];
  __shared__ __align__(16) unsigned short Bh[2][64][40], Bl[2][64][40];
  const int arow = tid >> 2;            // 0..63
  const int apart = (tid & 3) * 8;      // 8-elem (16 B) piece of a 32-elem row

  float4 a00, a01;
  u16x8 pb, plb;
#define LOADTILE(KT) do {                                                   \
    const size_t ko = (size_t)(KT) * 32 + apart;                            \
    const float* pa_ = A + (size_t)(m0 + arow) * 512 + ko;                  \
    a00 = *(const float4*)pa_;  a01 = *(const float4*)(pa_ + 4);            \
    pb  = *(const u16x8*)(BH + (size_t)(n0 + arow) * 512 + ko);             \
    plb = *(const u16x8*)(BL + (size_t)(n0 + arow) * 512 + ko);             \
  } while (0)
#define STORETILE(BUF) do {                                                 \
    u16x8 h0_, l0_;                                                         \
    split8(a00, a01, h0_, l0_);                                             \
    *(u16x8*)&Ah[BUF][arow][apart] = h0_;                                   \
    *(u16x8*)&Al[BUF][arow][apart] = l0_;                                   \
    *(u16x8*)&Bh[BUF][arow][apart] = pb;                                    \
    *(u16x8*)&Bl[BUF][arow][apart] = plb;                                   \
  } while (0)

  f32x4 accm[2][2], acce[2][2];
  #pragma unroll
  for (int mt = 0; mt < 2; ++mt)
    #pragma unroll
    for (int nt = 0; nt < 2; ++nt) {
      accm[mt][nt] = (f32x4){0.f, 0.f, 0.f, 0.f};
      acce[mt][nt] = (f32x4){0.f, 0.f, 0.f, 0.f};
    }

  LOADTILE(0);
  STORETILE(0);
  __syncthreads();

  for (int kt = 0; kt < 16; ++kt) {
    const int cur = kt & 1;
    if (kt + 1 < 16) LOADTILE(kt + 1);  // issue early; hides under compute
    bf16x8 ah[2], al[2], bh[2], bl[2];
    #pragma unroll
    for (int mt = 0; mt < 2; ++mt) {
      ah[mt] = *(const bf16x8*)&Ah[cur][wm * 32 + mt * 16 + r16][g * 8];
      al[mt] = *(const bf16x8*)&Al[cur][wm * 32 + mt * 16 + r16][g * 8];
    }
    #pragma unroll
    for (int nt = 0; nt < 2; ++nt) {
      bh[nt] = *(const bf16x8*)&Bh[cur][wn * 32 + nt * 16 + r16][g * 8];
      bl[nt] = *(const bf16x8*)&Bl[cur][wn * 32 + nt * 16 + r16][g * 8];
    }
    #pragma unroll
    for (int mt = 0; mt < 2; ++mt)
      #pragma unroll
      for (int nt = 0; nt < 2; ++nt) {
        accm[mt][nt] = __builtin_amdgcn_mfma_f32_16x16x32_bf16(ah[mt], bh[nt], accm[mt][nt], 0, 0, 0);
        acce[mt][nt] = __builtin_amdgcn_mfma_f32_16x16x32_bf16(al[mt], bh[nt], acce[mt][nt], 0, 0, 0);
        acce[mt][nt] = __builtin_amdgcn_mfma_f32_16x16x32_bf16(ah[mt], bl[nt], acce[mt][nt], 0, 0, 0);
      }
    if (kt + 1 < 16) STORETILE(cur ^ 1);  // other buffer: no hazard
    __syncthreads();                       // single barrier per k-tile
  }
#undef LOADTILE
#undef STORETILE

  #pragma unroll
  for (int mt = 0; mt < 2; ++mt)
    #pragma unroll
    for (int nt = 0; nt < 2; ++nt)
      #pragma unroll
      for (int jj = 0; jj < 4; ++jj) {
        float vsum = accm[mt][nt][jj] + acce[mt][nt][jj];
        int row = m0 + wm * 32 + mt * 16 + g * 4 + jj;
        int col = n0 + wn * 32 + nt * 16 + r16;
        C[(size_t)row * 512 + col] = __builtin_amdgcn_exp2f(vsum * K2SCALE);
      }
}

// ---- scores: s[b,q,t] = -2 * sum_f v[f]/(ew[t,f]*eu[q,f]+1) -------------------
// R16's packed-f32 q-pair tree + DPP butterfly, split out so the score phase
// runs at 8 waves/SIMD: grid = 8b x 64qt x 4tq = 2048 blocks x 256 thr (4
// waves, wave owns 16 t) -> 8 blocks/CU. __launch_bounds__(256, 8) caps VGPR
// at 64; the packed body MEASURES 48-52 (R16/R17), so no spill (unlike R8's
// ~90-VGPR scalar body, which kept the split at 4 waves/SIMD, or R9's cap-32
// spill disaster). L2 traffic unchanged: each block reads a 64-row ws slice.
__global__ __launch_bounds__(256, 8) void scores(
    const float* __restrict__ ws, const float* __restrict__ uh,
    const float* __restrict__ va, float* __restrict__ out_s)
{
  const int tid  = threadIdx.x;
  const int wave = tid >> 6;               // 0..3
  const int lane = tid & 63;
  const int blk  = blockIdx.x;
  const int b    = blk & 7;                // XCD-locality: batch <-> XCD
  const int rest = blk >> 3;               // 0..255
  const int q0   = (rest & 63) * QT;
  const int tq   = rest >> 6;              // 0..3
  const int t0   = tq * 64 + wave * 16;
  const int fbase = lane * 8;

  float4 v0 = *(const float4*)(va + fbase);
  float4 v1 = *(const float4*)(va + fbase + 4);
  float v[8] = {v0.x, v0.y, v0.z, v0.w, v1.x, v1.y, v1.z, v1.w};
  f32x2 vP[8];
  #pragma unroll
  for (int j = 0; j < 8; ++j) vP[j] = (f32x2){v[j], v[j]};

  // euP[p][j] = (eu[2p][j], eu[2p+1][j])
  f32x2 euP[2][8];
  #pragma unroll
  for (int p = 0; p < 2; ++p) {
    const float* up0 = uh + (size_t)(b * TD + q0 + 2 * p) * DE + fbase;
    const float* up1 = up0 + DE;
    float4 a0 = *(const float4*)(up0);
    float4 a1 = *(const float4*)(up0 + 4);
    float4 b0 = *(const float4*)(up1);
    float4 b1 = *(const float4*)(up1 + 4);
    float ea[8] = {a0.x, a0.y, a0.z, a0.w, a1.x, a1.y, a1.z, a1.w};
    float eb[8] = {b0.x, b0.y, b0.z, b0.w, b1.x, b1.y, b1.z, b1.w};
    #pragma unroll
    for (int j = 0; j < 8; ++j) euP[p][j] = (f32x2){ea[j], eb[j]};
  }
  const f32x2 one2 = {1.f, 1.f};

  // ---- wave owns t in [t0, t0+16), 1-deep prefetch on ws (R16 form) ----
  const float* wp = ws + (size_t)(b * TE + t0) * DE + fbase;
  float4 w0 = *(const float4*)(wp);
  float4 w1 = *(const float4*)(wp + 4);
  for (int t = t0; t < t0 + 16; ++t) {
    float cw[8] = {w0.x, w0.y, w0.z, w0.w, w1.x, w1.y, w1.z, w1.w};
    // prefetch next row; last iter (b=7,tq=3,wave=3) reads row 2048 = uh[0],
    // still inside the workspace allocation, unused.
    wp += DE;
    w0 = *(const float4*)(wp);
    w1 = *(const float4*)(wp + 4);
    f32x2 cw2[8];
    #pragma unroll
    for (int j = 0; j < 8; ++j) cw2[j] = (f32x2){cw[j], cw[j]};
    float a[QT];
    #pragma unroll
    for (int p = 0; p < 2; ++p) {
      f32x2 A0 = __builtin_elementwise_fma(cw2[0], euP[p][0], one2);
      f32x2 A1 = __builtin_elementwise_fma(cw2[1], euP[p][1], one2);
      f32x2 A2 = __builtin_elementwise_fma(cw2[2], euP[p][2], one2);
      f32x2 A3 = __builtin_elementwise_fma(cw2[3], euP[p][3], one2);
      f32x2 B0 = __builtin_elementwise_fma(cw2[4], euP[p][4], one2);
      f32x2 B1 = __builtin_elementwise_fma(cw2[5], euP[p][5], one2);
      f32x2 B2 = __builtin_elementwise_fma(cw2[6], euP[p][6], one2);
      f32x2 B3 = __builtin_elementwise_fma(cw2[7], euP[p][7], one2);
      f32x2 n1 = __builtin_elementwise_fma(vP[1], A0, vP[0] * A1);
      f32x2 d1 = A0 * A1;
      f32x2 n2 = __builtin_elementwise_fma(vP[3], A2, vP[2] * A3);
      f32x2 d2 = A2 * A3;
      f32x2 N1 = __builtin_elementwise_fma(n2, d1, n1 * d2);
      f32x2 D1 = d1 * d2;
      f32x2 n3 = __builtin_elementwise_fma(vP[5], B0, vP[4] * B1);
      f32x2 d3 = B0 * B1;
      f32x2 n4 = __builtin_elementwise_fma(vP[7], B2, vP[6] * B3);
      f32x2 d4 = B2 * B3;
      f32x2 N2 = __builtin_elementwise_fma(n4, d3, n3 * d4);
      f32x2 D2 = d3 * d4;
      float s0 = N1.x * __builtin_amdgcn_rcpf(D1.x);
      a[2 * p + 0] = fmaf(N2.x, __builtin_amdgcn_rcpf(D2.x), s0);
      float s1 = N1.y * __builtin_amdgcn_rcpf(D1.y);
      a[2 * p + 1] = fmaf(N2.y, __builtin_amdgcn_rcpf(D2.y), s1);
    }
    // reduction tree: DPP for levels 1,2,4,8; DS only for xor16/xor32.
    {
      const bool h1 = lane & 1;
      float m0 = h1 ? a[1] : a[0], o0 = h1 ? a[0] : a[1];
      float m1 = h1 ? a[3] : a[2], o1 = h1 ? a[2] : a[3];
      float r0 = m0 + dpp_mov<0xB1>(o0);    // quad_perm [1,0,3,2] == xor1
      float r1 = m1 + dpp_mov<0xB1>(o1);
      const bool h2 = lane & 2;
      float mm = h2 ? r1 : r0, oo = h2 ? r0 : r1;
      float r = mm + dpp_mov<0x4E>(oo);     // quad_perm [2,3,0,1] == xor2
      r += dpp_mov<0x124>(r);               // row_ror:4  (sum quads)
      r += dpp_mov<0x128>(r);               // row_ror:8
      r += __shfl_xor(r, 16, 64);
      r += __shfl_xor(r, 32, 64);
      if (lane < QT)
        out_s[(size_t)(b * TD + q0 + lane) * TE + t] = -2.f * r;
    }
  }
}

// ---- attn2: softmax + context (scores from global) ----------------------------
// grid = 8b x 64qt = 512 blocks x 512 thr; b = blk&7 XCD swizzle.
__global__ __launch_bounds__(512) void attn2(
    const float* __restrict__ gs, const float* __restrict__ enc,
    float* __restrict__ out_c, float* __restrict__ out_e)
{
  const int tid  = threadIdx.x;
  const int wave = tid >> 6;
  const int lane = tid & 63;
  const int b  = blockIdx.x & 7;
  const int q0 = (blockIdx.x >> 3) * QT;
  __shared__ float s_sc[QT][TE];           // 4 KB
  __shared__ float red[3][QT][DE];         // 24 KB, context partials

  // ---- softmax: waves 0..3 handle row = wave ----
  if (wave < QT) {
    const int r = wave;
    const float* row = gs + (size_t)(b * TD + q0 + r) * TE;
    float x[4];
    #pragma unroll
    for (int i = 0; i < 4; ++i) x[i] = row[lane + 64 * i];
    float m = fmaxf(fmaxf(x[0], x[1]), fmaxf(x[2], x[3]));
    #pragma unroll
    for (int off = 32; off >= 1; off >>= 1) m = fmaxf(m, __shfl_xor(m, off, 64));
    const float L2E = 1.4426950408889634f;
    float ssum = 0.f;
    #pragma unroll
    for (int i = 0; i < 4; ++i) { x[i] = __builtin_amdgcn_exp2f((x[i] - m) * L2E); ssum += x[i]; }
    #pragma unroll
    for (int off = 32; off >= 1; off >>= 1) ssum += __shfl_xor(ssum, off, 64);
    float inv = 1.f / ssum;
    float* oe = out_e + (size_t)(b * TD + q0 + r) * TE;
    #pragma unroll
    for (int i = 0; i < 4; ++i) {
      float e = x[i] * inv;
      s_sc[r][lane + 64 * i] = e;
      oe[lane + 64 * i] = e;
    }
  }
  __syncthreads();

  // ---- context: c[q][f4..f4+3] = sum_t e[q][t]*enc[b][t][f4..f4+3] ----
  {
    const int fgrp = tid >> 7;           // 0..3
    const int f4   = (tid & 127) * 4;
    float4 c[QT];
    #pragma unroll
    for (int q = 0; q < QT; ++q) c[q] = make_float4(0.f, 0.f, 0.f, 0.f);
    const float* eb = enc + (size_t)b * TE * DE + f4;
    const int tb = fgrp * 64;
    #pragma unroll 4
    for (int t = tb; t < tb + 64; ++t) {
      float4 ee = *(const float4*)(eb + (size_t)t * DE);
      #pragma unroll
      for (int q = 0; q < QT; ++q) {
        float w = s_sc[q][t];
        c[q].x = fmaf(w, ee.x, c[q].x);
        c[q].y = fmaf(w, ee.y, c[q].y);
        c[q].z = fmaf(w, ee.z, c[q].z);
        c[q].w = fmaf(w, ee.w, c[q].w);
      }
    }
    if (fgrp > 0) {
      #pragma unroll
      for (int q = 0; q < QT; ++q) *(float4*)&red[fgrp - 1][q][f4] = c[q];
    }
    __syncthreads();
    if (fgrp == 0) {
      #pragma unroll
      for (int q = 0; q < QT; ++q) {
        float4 r1 = *(const float4*)&red[0][q][f4];
        float4 r2 = *(const float4*)&red[1][q][f4];
        float4 r3 = *(const float4*)&red[2][q][f4];
        c[q].x += (r1.x + r2.x) + r3.x;
        c[q].y += (r1.y + r2.y) + r3.y;
        c[q].z += (r1.z + r2.z) + r3.z;
        c[q].w += (r1.w + r2.w) + r3.w;
        *(float4*)(out_c + (size_t)(b * TD + q0 + q) * DE + f4) = c[q];
      }
    }
  }
}

extern "C" void kernel_launch(void* const* d_in, const int* in_sizes, int n_in,
                              void* d_out, int out_size, void* d_ws, size_t ws_size,
                              hipStream_t stream) {
  const float* enc = (const float*)d_in[0];
  const float* dec = (const float*)d_in[1];
  const float* Wa  = (const float*)d_in[2];
  const float* Ua  = (const float*)d_in[3];
  const float* Va  = (const float*)d_in[4];
  float* out_c = (float*)d_out;
  float* out_e = out_c + (size_t)NB * TD * DE;          // c first, then e

  // workspace layout (12 MB):
  float* ws = (float*)d_ws;                             // ew = e^{2Ws}: 4 MB
  float* uh = ws + 1048576;                             // eu = e^{2Uh}: 4 MB
  unsigned short* BHw = (unsigned short*)(uh + 1048576);// 0.5 MB each
  unsigned short* BLw = BHw + 262144;
  unsigned short* BHu = BLw + 262144;
  unsigned short* BLu = BHu + 262144;
  float* gsc = (float*)(BLu + 262144);                  // scores: 2 MB

  convB<<<dim3(16, 16, 2), dim3(256), 0, stream>>>(Wa, BHw, BLw, Ua, BHu, BLu);
  gemm_mfma<<<dim3(8, 32, 2), dim3(256), 0, stream>>>(
      enc, BHw, BLw, ws, dec, BHu, BLu, uh);
  scores<<<dim3(NB * (TD / QT) * 4), dim3(256), 0, stream>>>(ws, uh, Va, gsc);
  attn2<<<dim3(NB * (TD / QT)), dim3(512), 0, stream>>>(gsc, enc, out_c, out_e);
}

// Round 19
// 67.274 us; speedup vs baseline: 1.5848x; 1.5848x over previous
//
#include <hip/hip_runtime.h>

#define NB 8
#define TE 256
#define TD 256
#define DE 512
#define QT 4

// K2 = 2*log2(e): exp2(K2*x) = e^{2x}; tanh(x) = 1 - 2/(e^{2x}+1).
#define K2SCALE 2.8853900817779268f

typedef short bf16x8 __attribute__((ext_vector_type(8)));           // 8 bf16 (4 VGPR)
typedef float f32x4 __attribute__((ext_vector_type(4)));            // MFMA acc
typedef float f32x2 __attribute__((ext_vector_type(2)));            // v_pk_*_f32 pair
typedef unsigned short u16x8 __attribute__((ext_vector_type(8)));   // 16 B staging

// round-to-nearest-even f32 -> bf16
static __device__ __forceinline__ unsigned short f2bf(float x) {
  unsigned int u = __float_as_uint(x);
  u += 0x7fffu + ((u >> 16) & 1u);
  return (unsigned short)(u >> 16);
}

// split f32 -> hi (ROUNDED bf16) + lo (rounded residual).
static __device__ __forceinline__ void split8(
    const float4& x0, const float4& x1, u16x8& h, u16x8& l) {
  float xs[8] = {x0.x, x0.y, x0.z, x0.w, x1.x, x1.y, x1.z, x1.w};
  #pragma unroll
  for (int j = 0; j < 8; ++j) {
    unsigned short hh = f2bf(xs[j]);
    float hf = __uint_as_float((unsigned int)hh << 16);
    h[j] = hh;
    l[j] = f2bf(xs[j] - hf);
  }
}

// DPP cross-lane fetch at full VALU rate (no DS, no lgkmcnt chain).
// 0xB1 = quad_perm[1,0,3,2] (xor1), 0x4E = quad_perm[2,3,0,1] (xor2),
// 0x124 = row_ror:4, 0x128 = row_ror:8 (within 16-lane row).
template <int CTRL>
static __device__ __forceinline__ float dpp_mov(float x) {
  return __int_as_float(__builtin_amdgcn_update_dpp(
      0, __float_as_int(x), CTRL, 0xf, 0xf, true));
}

// ---- convB: W [512x512] f32 -> TRANSPOSED hi/lo bf16 BT[n][k] (32x32 tiles) ----
// grid (16, 16, 2), 256 thr.  (R6-exact: chain minimum)
__global__ __launch_bounds__(256) void convB(
    const float* __restrict__ w0, unsigned short* __restrict__ h0, unsigned short* __restrict__ l0,
    const float* __restrict__ w1, unsigned short* __restrict__ h1, unsigned short* __restrict__ l1)
{
  const float* W = blockIdx.z ? w1 : w0;
  unsigned short* H = blockIdx.z ? h1 : h0;
  unsigned short* L = blockIdx.z ? l1 : l0;
  __shared__ unsigned short sh[32][33], sl[32][33];
  const int t = threadIdx.x;
  const int k0 = blockIdx.y * 32, n0 = blockIdx.x * 32;
  const int r = t >> 3, c = (t & 7) * 4;
  float4 x = *(const float4*)(W + (size_t)(k0 + r) * DE + n0 + c);
  float xs[4] = {x.x, x.y, x.z, x.w};
  #pragma unroll
  for (int j = 0; j < 4; ++j) {
    unsigned short hh = f2bf(xs[j]);
    float hf = __uint_as_float((unsigned int)hh << 16);
    sh[r][c + j] = hh;
    sl[r][c + j] = f2bf(xs[j] - hf);
  }
  __syncthreads();
  ushort4 oh, ol;
  oh.x = sh[c + 0][r]; oh.y = sh[c + 1][r]; oh.z = sh[c + 2][r]; oh.w = sh[c + 3][r];
  ol.x = sl[c + 0][r]; ol.y = sl[c + 1][r]; ol.z = sl[c + 2][r]; ol.w = sl[c + 3][r];
  *(ushort4*)(H + (size_t)(n0 + r) * DE + k0 + c) = oh;
  *(ushort4*)(L + (size_t)(n0 + r) * DE + k0 + c) = ol;
}

// ---- gemm_mfma: C = exp2(K2 * A@B), A f32 split in-register, dbuf LDS ---------
// R6-exact: BM=64 BN=64 KT=32, 256 thr (4 waves 2x2), wave-tile 32x32,
// grid (8, 32, 2) 2D decode.
__global__ __launch_bounds__(256) void gemm_mfma(
    const float* __restrict__ A0,
    const unsigned short* __restrict__ BH0, const unsigned short* __restrict__ BL0,
    float* __restrict__ C0,
    const float* __restrict__ A1,
    const unsigned short* __restrict__ BH1, const unsigned short* __restrict__ BL1,
    float* __restrict__ C1)
{
  const float*          A  = blockIdx.z ? A1  : A0;
  const unsigned short* BH = blockIdx.z ? BH1 : BH0;
  const unsigned short* BL = blockIdx.z ? BL1 : BL0;
  float*                C  = blockIdx.z ? C1  : C0;
  const int tid  = threadIdx.x;
  const int lane = tid & 63;
  const int wave = tid >> 6;
  const int wm = wave >> 1, wn = wave & 1;
  const int g = lane >> 4, r16 = lane & 15;
  const int m0 = blockIdx.y * 64, n0 = blockIdx.x * 64;
  __shared__ __align__(16) unsigned short Ah[2][64][40], Al[2][64][40];
  __shared__ __align__(16) unsigned short Bh[2][64][40], Bl[2][64][40];
  const int arow = tid >> 2;            // 0..63
  const int apart = (tid & 3) * 8;      // 8-elem (16 B) piece of a 32-elem row

  float4 a00, a01;
  u16x8 pb, plb;
#define LOADTILE(KT) do {                                                   \
    const size_t ko = (size_t)(KT) * 32 + apart;                            \
    const float* pa_ = A + (size_t)(m0 + arow) * 512 + ko;                  \
    a00 = *(const float4*)pa_;  a01 = *(const float4*)(pa_ + 4);            \
    pb  = *(const u16x8*)(BH + (size_t)(n0 + arow) * 512 + ko);             \
    plb = *(const u16x8*)(BL + (size_t)(n0 + arow) * 512 + ko);             \
  } while (0)
#define STORETILE(BUF) do {                                                 \
    u16x8 h0_, l0_;                                                         \
    split8(a00, a01, h0_, l0_);                                             \
    *(u16x8*)&Ah[BUF][arow][apart] = h0_;                                   \
    *(u16x8*)&Al[BUF][arow][apart] = l0_;                                   \
    *(u16x8*)&Bh[BUF][arow][apart] = pb;                                    \
    *(u16x8*)&Bl[BUF][arow][apart] = plb;                                   \
  } while (0)

  f32x4 accm[2][2], acce[2][2];
  #pragma unroll
  for (int mt = 0; mt < 2; ++mt)
    #pragma unroll
    for (int nt = 0; nt < 2; ++nt) {
      accm[mt][nt] = (f32x4){0.f, 0.f, 0.f, 0.f};
      acce[mt][nt] = (f32x4){0.f, 0.f, 0.f, 0.f};
    }

  LOADTILE(0);
  STORETILE(0);
  __syncthreads();

  for (int kt = 0; kt < 16; ++kt) {
    const int cur = kt & 1;
    if (kt + 1 < 16) LOADTILE(kt + 1);  // issue early; hides under compute
    bf16x8 ah[2], al[2], bh[2], bl[2];
    #pragma unroll
    for (int mt = 0; mt < 2; ++mt) {
      ah[mt] = *(const bf16x8*)&Ah[cur][wm * 32 + mt * 16 + r16][g * 8];
      al[mt] = *(const bf16x8*)&Al[cur][wm * 32 + mt * 16 + r16][g * 8];
    }
    #pragma unroll
    for (int nt = 0; nt < 2; ++nt) {
      bh[nt] = *(const bf16x8*)&Bh[cur][wn * 32 + nt * 16 + r16][g * 8];
      bl[nt] = *(const bf16x8*)&Bl[cur][wn * 32 + nt * 16 + r16][g * 8];
    }
    #pragma unroll
    for (int mt = 0; mt < 2; ++mt)
      #pragma unroll
      for (int nt = 0; nt < 2; ++nt) {
        accm[mt][nt] = __builtin_amdgcn_mfma_f32_16x16x32_bf16(ah[mt], bh[nt], accm[mt][nt], 0, 0, 0);
        acce[mt][nt] = __builtin_amdgcn_mfma_f32_16x16x32_bf16(al[mt], bh[nt], acce[mt][nt], 0, 0, 0);
        acce[mt][nt] = __builtin_amdgcn_mfma_f32_16x16x32_bf16(ah[mt], bl[nt], acce[mt][nt], 0, 0, 0);
      }
    if (kt + 1 < 16) STORETILE(cur ^ 1);  // other buffer: no hazard
    __syncthreads();                       // single barrier per k-tile
  }
#undef LOADTILE
#undef STORETILE

  #pragma unroll
  for (int mt = 0; mt < 2; ++mt)
    #pragma unroll
    for (int nt = 0; nt < 2; ++nt)
      #pragma unroll
      for (int jj = 0; jj < 4; ++jj) {
        float vsum = accm[mt][nt][jj] + acce[mt][nt][jj];
        int row = m0 + wm * 32 + mt * 16 + g * 4 + jj;
        int col = n0 + wn * 32 + nt * 16 + r16;
        C[(size_t)row * 512 + col] = __builtin_amdgcn_exp2f(vsum * K2SCALE);
      }
}

// ---------------- fused scores + softmax + context -----------------------------
// R16 body (packed-f32 q-pair tree + DPP butterfly + 1-deep prefetch), ONE
// structural change: 768 threads (12 waves) per block -> 2 blocks/CU = 24
// waves/CU = 6 waves/SIMD (was 4). __launch_bounds__(768, 6) caps VGPR at 85,
// comfortably >= the measured 48-52 body -> no spill (the R9/R18 failure mode).
// LDS 44 KB (s_sc 4K + red[5] 40K): 2x44=88 <= 160, 1536 thr <= 2048 -> both
// blocks resident (unlike R15's 60 KB 16-wave blocks). Score phase is
// t-strided (t = wave; t += 12); context uses 6 f-groups with 43/42 t-split.
__global__ __launch_bounds__(768, 6) void attn(
    const float* __restrict__ ws, const float* __restrict__ uh,
    const float* __restrict__ enc, const float* __restrict__ va,
    float* __restrict__ out_c, float* __restrict__ out_e)
{
  const int tid  = threadIdx.x;
  const int wave = tid >> 6;               // 0..11
  const int lane = tid & 63;
  const int b  = blockIdx.x & 7;           // XCD-locality: batch <-> XCD
  const int q0 = (blockIdx.x >> 3) * QT;
  __shared__ float s_sc[QT][TE];           // 4 KB
  __shared__ float red[5][QT][DE];         // 40 KB, context partials
  const int fbase = lane * 8;              // lane owns 8 contiguous f

  float4 v0 = *(const float4*)(va + fbase);
  float4 v1 = *(const float4*)(va + fbase + 4);
  float v[8] = {v0.x, v0.y, v0.z, v0.w, v1.x, v1.y, v1.z, v1.w};
  f32x2 vP[8];
  #pragma unroll
  for (int j = 0; j < 8; ++j) vP[j] = (f32x2){v[j], v[j]};

  // euP[p][j] = (eu[2p][j], eu[2p+1][j])
  f32x2 euP[2][8];
  #pragma unroll
  for (int p = 0; p < 2; ++p) {
    const float* up0 = uh + (size_t)(b * TD + q0 + 2 * p) * DE + fbase;
    const float* up1 = up0 + DE;
    float4 a0 = *(const float4*)(up0);
    float4 a1 = *(const float4*)(up0 + 4);
    float4 b0 = *(const float4*)(up1);
    float4 b1 = *(const float4*)(up1 + 4);
    float ea[8] = {a0.x, a0.y, a0.z, a0.w, a1.x, a1.y, a1.z, a1.w};
    float eb[8] = {b0.x, b0.y, b0.z, b0.w, b1.x, b1.y, b1.z, b1.w};
    #pragma unroll
    for (int j = 0; j < 8; ++j) euP[p][j] = (f32x2){ea[j], eb[j]};
  }
  const f32x2 one2 = {1.f, 1.f};

  // ---- scores: wave owns t = wave, wave+12, ... ; 1-deep prefetch on ws ----
  // Last prefetch reads row (t_last + 12) <= 267 -> lands in uh rows 0..11,
  // still inside the workspace allocation, unused.
  {
    const float* wp = ws + (size_t)(b * TE + wave) * DE + fbase;
    float4 w0 = *(const float4*)(wp);
    float4 w1 = *(const float4*)(wp + 4);
    for (int t = wave; t < TE; t += 12) {
      float cw[8] = {w0.x, w0.y, w0.z, w0.w, w1.x, w1.y, w1.z, w1.w};
      wp += 12 * DE;                       // prefetch row t+12
      w0 = *(const float4*)(wp);
      w1 = *(const float4*)(wp + 4);
      f32x2 cw2[8];
      #pragma unroll
      for (int j = 0; j < 8; ++j) cw2[j] = (f32x2){cw[j], cw[j]};
      float a[QT];
      #pragma unroll
      for (int p = 0; p < 2; ++p) {
        f32x2 A0 = __builtin_elementwise_fma(cw2[0], euP[p][0], one2);
        f32x2 A1 = __builtin_elementwise_fma(cw2[1], euP[p][1], one2);
        f32x2 A2 = __builtin_elementwise_fma(cw2[2], euP[p][2], one2);
        f32x2 A3 = __builtin_elementwise_fma(cw2[3], euP[p][3], one2);
        f32x2 B0 = __builtin_elementwise_fma(cw2[4], euP[p][4], one2);
        f32x2 B1 = __builtin_elementwise_fma(cw2[5], euP[p][5], one2);
        f32x2 B2 = __builtin_elementwise_fma(cw2[6], euP[p][6], one2);
        f32x2 B3 = __builtin_elementwise_fma(cw2[7], euP[p][7], one2);
        f32x2 n1 = __builtin_elementwise_fma(vP[1], A0, vP[0] * A1);
        f32x2 d1 = A0 * A1;
        f32x2 n2 = __builtin_elementwise_fma(vP[3], A2, vP[2] * A3);
        f32x2 d2 = A2 * A3;
        f32x2 N1 = __builtin_elementwise_fma(n2, d1, n1 * d2);
        f32x2 D1 = d1 * d2;
        f32x2 n3 = __builtin_elementwise_fma(vP[5], B0, vP[4] * B1);
        f32x2 d3 = B0 * B1;
        f32x2 n4 = __builtin_elementwise_fma(vP[7], B2, vP[6] * B3);
        f32x2 d4 = B2 * B3;
        f32x2 N2 = __builtin_elementwise_fma(n4, d3, n3 * d4);
        f32x2 D2 = d3 * d4;
        float s0 = N1.x * __builtin_amdgcn_rcpf(D1.x);
        a[2 * p + 0] = fmaf(N2.x, __builtin_amdgcn_rcpf(D2.x), s0);
        float s1 = N1.y * __builtin_amdgcn_rcpf(D1.y);
        a[2 * p + 1] = fmaf(N2.y, __builtin_amdgcn_rcpf(D2.y), s1);
      }
      // reduction tree: DPP for levels 1,2,4,8; DS only for xor16/xor32.
      {
        const bool h1 = lane & 1;
        float m0 = h1 ? a[1] : a[0], o0 = h1 ? a[0] : a[1];
        float m1 = h1 ? a[3] : a[2], o1 = h1 ? a[2] : a[3];
        float r0 = m0 + dpp_mov<0xB1>(o0);    // quad_perm [1,0,3,2] == xor1
        float r1 = m1 + dpp_mov<0xB1>(o1);
        const bool h2 = lane & 2;
        float mm = h2 ? r1 : r0, oo = h2 ? r0 : r1;
        float r = mm + dpp_mov<0x4E>(oo);     // quad_perm [2,3,0,1] == xor2
        r += dpp_mov<0x124>(r);               // row_ror:4  (sum quads)
        r += dpp_mov<0x128>(r);               // row_ror:8
        r += __shfl_xor(r, 16, 64);
        r += __shfl_xor(r, 32, 64);
        if (lane < QT) s_sc[lane][t] = -2.f * r;
      }
    }
  }
  __syncthreads();

  // ---- softmax: waves 0..3 handle row = wave; waves 4..11 wait ----
  if (wave < QT) {
    const int r = wave;
    float x[4];
    #pragma unroll
    for (int i = 0; i < 4; ++i) x[i] = s_sc[r][lane + 64 * i];
    float m = fmaxf(fmaxf(x[0], x[1]), fmaxf(x[2], x[3]));
    #pragma unroll
    for (int off = 32; off >= 1; off >>= 1) m = fmaxf(m, __shfl_xor(m, off, 64));
    const float L2E = 1.4426950408889634f;
    float ssum = 0.f;
    #pragma unroll
    for (int i = 0; i < 4; ++i) { x[i] = __builtin_amdgcn_exp2f((x[i] - m) * L2E); ssum += x[i]; }
    #pragma unroll
    for (int off = 32; off >= 1; off >>= 1) ssum += __shfl_xor(ssum, off, 64);
    float inv = 1.f / ssum;
    float* oe = out_e + (size_t)(b * TD + q0 + r) * TE;
    #pragma unroll
    for (int i = 0; i < 4; ++i) {
      float e = x[i] * inv;
      s_sc[r][lane + 64 * i] = e;
      oe[lane + 64 * i] = e;
    }
  }
  __syncthreads();

  // ---- context: c[q][f4..f4+3] = sum_t e[q][t]*enc[b][t][f4..f4+3] ----
  // 6 f-groups of 128 threads; group g owns t in [tb, te): 43,43,43,43,42,42.
  {
    const int fgrp = tid >> 7;           // 0..5
    const int f4   = (tid & 127) * 4;
    const int tb   = fgrp * 43 - (fgrp > 4 ? (fgrp - 4) : 0);
    const int te   = tb + (fgrp < 4 ? 43 : 42);
    float4 c[QT];
    #pragma unroll
    for (int q = 0; q < QT; ++q) c[q] = make_float4(0.f, 0.f, 0.f, 0.f);
    const float* eb = enc + (size_t)b * TE * DE + f4;
    for (int t = tb; t < te; ++t) {
      float4 ee = *(const float4*)(eb + (size_t)t * DE);
      #pragma unroll
      for (int q = 0; q < QT; ++q) {
        float w = s_sc[q][t];
        c[q].x = fmaf(w, ee.x, c[q].x);
        c[q].y = fmaf(w, ee.y, c[q].y);
        c[q].z = fmaf(w, ee.z, c[q].z);
        c[q].w = fmaf(w, ee.w, c[q].w);
      }
    }
    if (fgrp > 0) {
      #pragma unroll
      for (int q = 0; q < QT; ++q) *(float4*)&red[fgrp - 1][q][f4] = c[q];
    }
    __syncthreads();
    if (fgrp == 0) {
      #pragma unroll
      for (int q = 0; q < QT; ++q) {
        float4 acc = c[q];
        #pragma unroll
        for (int p = 0; p < 5; ++p) {
          float4 rr = *(const float4*)&red[p][q][f4];
          acc.x += rr.x; acc.y += rr.y; acc.z += rr.z; acc.w += rr.w;
        }
        *(float4*)(out_c + (size_t)(b * TD + q0 + q) * DE + f4) = acc;
      }
    }
  }
}

extern "C" void kernel_launch(void* const* d_in, const int* in_sizes, int n_in,
                              void* d_out, int out_size, void* d_ws, size_t ws_size,
                              hipStream_t stream) {
  const float* enc = (const float*)d_in[0];
  const float* dec = (const float*)d_in[1];
  const float* Wa  = (const float*)d_in[2];
  const float* Ua  = (const float*)d_in[3];
  const float* Va  = (const float*)d_in[4];
  float* out_c = (float*)d_out;
  float* out_e = out_c + (size_t)NB * TD * DE;          // c first, then e

  // workspace layout (10 MB):
  float* ws = (float*)d_ws;                             // ew = e^{2Ws}: 4 MB
  float* uh = ws + 1048576;                             // eu = e^{2Uh}: 4 MB
  unsigned short* BHw = (unsigned short*)(uh + 1048576);// 0.5 MB each
  unsigned short* BLw = BHw + 262144;
  unsigned short* BHu = BLw + 262144;
  unsigned short* BLu = BHu + 262144;

  convB<<<dim3(16, 16, 2), dim3(256), 0, stream>>>(Wa, BHw, BLw, Ua, BHu, BLu);
  gemm_mfma<<<dim3(8, 32, 2), dim3(256), 0, stream>>>(
      enc, BHw, BLw, ws, dec, BHu, BLu, uh);
  attn<<<dim3(NB * (TD / QT)), dim3(768), 0, stream>>>(
      ws, uh, enc, Va, out_c, out_e);
}

// Round 20
// 65.436 us; speedup vs baseline: 1.6293x; 1.0281x over previous
//
#include <hip/hip_runtime.h>

#define NB 8
#define TE 256
#define TD 256
#define DE 512
#define QT 4

// K2 = 2*log2(e): exp2(K2*x) = e^{2x}; tanh(x) = 1 - 2/(e^{2x}+1).
#define K2SCALE 2.8853900817779268f

typedef short bf16x8 __attribute__((ext_vector_type(8)));           // 8 bf16 (4 VGPR)
typedef float f32x4 __attribute__((ext_vector_type(4)));            // MFMA acc
typedef float f32x2 __attribute__((ext_vector_type(2)));            // v_pk_*_f32 pair
typedef unsigned short u16x8 __attribute__((ext_vector_type(8)));   // 16 B staging

// round-to-nearest-even f32 -> bf16
static __device__ __forceinline__ unsigned short f2bf(float x) {
  unsigned int u = __float_as_uint(x);
  u += 0x7fffu + ((u >> 16) & 1u);
  return (unsigned short)(u >> 16);
}

// split f32 -> hi (ROUNDED bf16) + lo (rounded residual).
static __device__ __forceinline__ void split8(
    const float4& x0, const float4& x1, u16x8& h, u16x8& l) {
  float xs[8] = {x0.x, x0.y, x0.z, x0.w, x1.x, x1.y, x1.z, x1.w};
  #pragma unroll
  for (int j = 0; j < 8; ++j) {
    unsigned short hh = f2bf(xs[j]);
    float hf = __uint_as_float((unsigned int)hh << 16);
    h[j] = hh;
    l[j] = f2bf(xs[j] - hf);
  }
}

// DPP cross-lane fetch at full VALU rate (no DS, no lgkmcnt chain).
// 0xB1 = quad_perm[1,0,3,2] (xor1), 0x4E = quad_perm[2,3,0,1] (xor2),
// 0x124 = row_ror:4, 0x128 = row_ror:8 (within 16-lane row).
template <int CTRL>
static __device__ __forceinline__ float dpp_mov(float x) {
  return __int_as_float(__builtin_amdgcn_update_dpp(
      0, __float_as_int(x), CTRL, 0xf, 0xf, true));
}

// ---- convB: W [512x512] f32 -> TRANSPOSED hi/lo bf16 BT[n][k] (32x32 tiles) ----
// grid (16, 16, 2), 256 thr.  (R6-exact: chain minimum)
__global__ __launch_bounds__(256) void convB(
    const float* __restrict__ w0, unsigned short* __restrict__ h0, unsigned short* __restrict__ l0,
    const float* __restrict__ w1, unsigned short* __restrict__ h1, unsigned short* __restrict__ l1)
{
  const float* W = blockIdx.z ? w1 : w0;
  unsigned short* H = blockIdx.z ? h1 : h0;
  unsigned short* L = blockIdx.z ? l1 : l0;
  __shared__ unsigned short sh[32][33], sl[32][33];
  const int t = threadIdx.x;
  const int k0 = blockIdx.y * 32, n0 = blockIdx.x * 32;
  const int r = t >> 3, c = (t & 7) * 4;
  float4 x = *(const float4*)(W + (size_t)(k0 + r) * DE + n0 + c);
  float xs[4] = {x.x, x.y, x.z, x.w};
  #pragma unroll
  for (int j = 0; j < 4; ++j) {
    unsigned short hh = f2bf(xs[j]);
    float hf = __uint_as_float((unsigned int)hh << 16);
    sh[r][c + j] = hh;
    sl[r][c + j] = f2bf(xs[j] - hf);
  }
  __syncthreads();
  ushort4 oh, ol;
  oh.x = sh[c + 0][r]; oh.y = sh[c + 1][r]; oh.z = sh[c + 2][r]; oh.w = sh[c + 3][r];
  ol.x = sl[c + 0][r]; ol.y = sl[c + 1][r]; ol.z = sl[c + 2][r]; ol.w = sl[c + 3][r];
  *(ushort4*)(H + (size_t)(n0 + r) * DE + k0 + c) = oh;
  *(ushort4*)(L + (size_t)(n0 + r) * DE + k0 + c) = ol;
}

// ---- gemm_mfma: C = exp2(K2 * A@B), A f32 split in-register, dbuf LDS ---------
// R6-exact: BM=64 BN=64 KT=32, 256 thr (4 waves 2x2), wave-tile 32x32,
// grid (8, 32, 2) 2D decode.
__global__ __launch_bounds__(256) void gemm_mfma(
    const float* __restrict__ A0,
    const unsigned short* __restrict__ BH0, const unsigned short* __restrict__ BL0,
    float* __restrict__ C0,
    const float* __restrict__ A1,
    const unsigned short* __restrict__ BH1, const unsigned short* __restrict__ BL1,
    float* __restrict__ C1)
{
  const float*          A  = blockIdx.z ? A1  : A0;
  const unsigned short* BH = blockIdx.z ? BH1 : BH0;
  const unsigned short* BL = blockIdx.z ? BL1 : BL0;
  float*                C  = blockIdx.z ? C1  : C0;
  const int tid  = threadIdx.x;
  const int lane = tid & 63;
  const int wave = tid >> 6;
  const int wm = wave >> 1, wn = wave & 1;
  const int g = lane >> 4, r16 = lane & 15;
  const int m0 = blockIdx.y * 64, n0 = blockIdx.x * 64;
  __shared__ __align__(16) unsigned short Ah[2][64][40], Al[2][64][40];
  __shared__ __align__(16) unsigned short Bh[2][64][40], Bl[2][64][40];
  const int arow = tid >> 2;            // 0..63
  const int apart = (tid & 3) * 8;      // 8-elem (16 B) piece of a 32-elem row

  float4 a00, a01;
  u16x8 pb, plb;
#define LOADTILE(KT) do {                                                   \
    const size_t ko = (size_t)(KT) * 32 + apart;                            \
    const float* pa_ = A + (size_t)(m0 + arow) * 512 + ko;                  \
    a00 = *(const float4*)pa_;  a01 = *(const float4*)(pa_ + 4);            \
    pb  = *(const u16x8*)(BH + (size_t)(n0 + arow) * 512 + ko);             \
    plb = *(const u16x8*)(BL + (size_t)(n0 + arow) * 512 + ko);             \
  } while (0)
#define STORETILE(BUF) do {                                                 \
    u16x8 h0_, l0_;                                                         \
    split8(a00, a01, h0_, l0_);                                             \
    *(u16x8*)&Ah[BUF][arow][apart] = h0_;                                   \
    *(u16x8*)&Al[BUF][arow][apart] = l0_;                                   \
    *(u16x8*)&Bh[BUF][arow][apart] = pb;                                    \
    *(u16x8*)&Bl[BUF][arow][apart] = plb;                                   \
  } while (0)

  f32x4 accm[2][2], acce[2][2];
  #pragma unroll
  for (int mt = 0; mt < 2; ++mt)
    #pragma unroll
    for (int nt = 0; nt < 2; ++nt) {
      accm[mt][nt] = (f32x4){0.f, 0.f, 0.f, 0.f};
      acce[mt][nt] = (f32x4){0.f, 0.f, 0.f, 0.f};
    }

  LOADTILE(0);
  STORETILE(0);
  __syncthreads();

  for (int kt = 0; kt < 16; ++kt) {
    const int cur = kt & 1;
    if (kt + 1 < 16) LOADTILE(kt + 1);  // issue early; hides under compute
    bf16x8 ah[2], al[2], bh[2], bl[2];
    #pragma unroll
    for (int mt = 0; mt < 2; ++mt) {
      ah[mt] = *(const bf16x8*)&Ah[cur][wm * 32 + mt * 16 + r16][g * 8];
      al[mt] = *(const bf16x8*)&Al[cur][wm * 32 + mt * 16 + r16][g * 8];
    }
    #pragma unroll
    for (int nt = 0; nt < 2; ++nt) {
      bh[nt] = *(const bf16x8*)&Bh[cur][wn * 32 + nt * 16 + r16][g * 8];
      bl[nt] = *(const bf16x8*)&Bl[cur][wn * 32 + nt * 16 + r16][g * 8];
    }
    #pragma unroll
    for (int mt = 0; mt < 2; ++mt)
      #pragma unroll
      for (int nt = 0; nt < 2; ++nt) {
        accm[mt][nt] = __builtin_amdgcn_mfma_f32_16x16x32_bf16(ah[mt], bh[nt], accm[mt][nt], 0, 0, 0);
        acce[mt][nt] = __builtin_amdgcn_mfma_f32_16x16x32_bf16(al[mt], bh[nt], acce[mt][nt], 0, 0, 0);
        acce[mt][nt] = __builtin_amdgcn_mfma_f32_16x16x32_bf16(ah[mt], bl[nt], acce[mt][nt], 0, 0, 0);
      }
    if (kt + 1 < 16) STORETILE(cur ^ 1);  // other buffer: no hazard
    __syncthreads();                       // single barrier per k-tile
  }
#undef LOADTILE
#undef STORETILE

  #pragma unroll
  for (int mt = 0; mt < 2; ++mt)
    #pragma unroll
    for (int nt = 0; nt < 2; ++nt)
      #pragma unroll
      for (int jj = 0; jj < 4; ++jj) {
        float vsum = accm[mt][nt][jj] + acce[mt][nt][jj];
        int row = m0 + wm * 32 + mt * 16 + g * 4 + jj;
        int col = n0 + wn * 32 + nt * 16 + r16;
        C[(size_t)row * 512 + col] = __builtin_amdgcn_exp2f(vsum * K2SCALE);
      }
}

// ---------------- fused scores + softmax + context -----------------------------
// R16-exact structure (best measured: attn 43.9us): 512 thr / 8 waves, packed
// f32 q-pair tree, DPP butterfly, 1-deep ws prefetch, XCD-local b=blk&7.
// ONE micro-change vs R16: the -2 is folded into v at load (v enters every
// numerator linearly), deleting the per-t -2*r multiply. Occupancy ladder
// {4,6,8,16 waves/SIMD} is fully measured; 4 is the optimum (R9/R15/R18/R19).
__global__ __launch_bounds__(512, 4) void attn(
    const float* __restrict__ ws, const float* __restrict__ uh,
    const float* __restrict__ enc, const float* __restrict__ va,
    float* __restrict__ out_c, float* __restrict__ out_e)
{
  const int tid  = threadIdx.x;
  const int wave = tid >> 6;
  const int lane = tid & 63;
  const int b  = blockIdx.x & 7;           // XCD-locality: batch <-> XCD
  const int q0 = (blockIdx.x >> 3) * QT;
  __shared__ float s_sc[QT][TE];           // 4 KB
  __shared__ float red[3][QT][DE];         // 24 KB, context partials
  const int fbase = lane * 8;              // lane owns 8 contiguous f

  float4 v0 = *(const float4*)(va + fbase);
  float4 v1 = *(const float4*)(va + fbase + 4);
  // -2 folded in: s_sc stores sum of (-2 v[f]) * rcp(...) directly.
  float v[8] = {-2.f * v0.x, -2.f * v0.y, -2.f * v0.z, -2.f * v0.w,
                -2.f * v1.x, -2.f * v1.y, -2.f * v1.z, -2.f * v1.w};
  f32x2 vP[8];
  #pragma unroll
  for (int j = 0; j < 8; ++j) vP[j] = (f32x2){v[j], v[j]};

  // euP[p][j] = (eu[2p][j], eu[2p+1][j])
  f32x2 euP[2][8];
  #pragma unroll
  for (int p = 0; p < 2; ++p) {
    const float* up0 = uh + (size_t)(b * TD + q0 + 2 * p) * DE + fbase;
    const float* up1 = up0 + DE;
    float4 a0 = *(const float4*)(up0);
    float4 a1 = *(const float4*)(up0 + 4);
    float4 b0 = *(const float4*)(up1);
    float4 b1 = *(const float4*)(up1 + 4);
    float ea[8] = {a0.x, a0.y, a0.z, a0.w, a1.x, a1.y, a1.z, a1.w};
    float eb[8] = {b0.x, b0.y, b0.z, b0.w, b1.x, b1.y, b1.z, b1.w};
    #pragma unroll
    for (int j = 0; j < 8; ++j) euP[p][j] = (f32x2){ea[j], eb[j]};
  }
  const f32x2 one2 = {1.f, 1.f};

  // ---- scores: wave owns t in [wave*32, wave*32+32), 1-deep prefetch on ws ----
  const int t0 = wave * 32;
  const float* wp = ws + (size_t)(b * TE + t0) * DE + fbase;
  float4 w0 = *(const float4*)(wp);
  float4 w1 = *(const float4*)(wp + 4);
  for (int t = t0; t < t0 + 32; ++t) {
    float cw[8] = {w0.x, w0.y, w0.z, w0.w, w1.x, w1.y, w1.z, w1.w};
    // prefetch next row; last iteration reads one row past (lands in uh[0],
    // still inside the same workspace allocation) and is unused.
    wp += DE;
    w0 = *(const float4*)(wp);
    w1 = *(const float4*)(wp + 4);
    f32x2 cw2[8];
    #pragma unroll
    for (int j = 0; j < 8; ++j) cw2[j] = (f32x2){cw[j], cw[j]};
    float a[QT];
    #pragma unroll
    for (int p = 0; p < 2; ++p) {
      f32x2 A0 = __builtin_elementwise_fma(cw2[0], euP[p][0], one2);
      f32x2 A1 = __builtin_elementwise_fma(cw2[1], euP[p][1], one2);
      f32x2 A2 = __builtin_elementwise_fma(cw2[2], euP[p][2], one2);
      f32x2 A3 = __builtin_elementwise_fma(cw2[3], euP[p][3], one2);
      f32x2 B0 = __builtin_elementwise_fma(cw2[4], euP[p][4], one2);
      f32x2 B1 = __builtin_elementwise_fma(cw2[5], euP[p][5], one2);
      f32x2 B2 = __builtin_elementwise_fma(cw2[6], euP[p][6], one2);
      f32x2 B3 = __builtin_elementwise_fma(cw2[7], euP[p][7], one2);
      f32x2 n1 = __builtin_elementwise_fma(vP[1], A0, vP[0] * A1);
      f32x2 d1 = A0 * A1;
      f32x2 n2 = __builtin_elementwise_fma(vP[3], A2, vP[2] * A3);
      f32x2 d2 = A2 * A3;
      f32x2 N1 = __builtin_elementwise_fma(n2, d1, n1 * d2);
      f32x2 D1 = d1 * d2;
      f32x2 n3 = __builtin_elementwise_fma(vP[5], B0, vP[4] * B1);
      f32x2 d3 = B0 * B1;
      f32x2 n4 = __builtin_elementwise_fma(vP[7], B2, vP[6] * B3);
      f32x2 d4 = B2 * B3;
      f32x2 N2 = __builtin_elementwise_fma(n4, d3, n3 * d4);
      f32x2 D2 = d3 * d4;
      float s0 = N1.x * __builtin_amdgcn_rcpf(D1.x);
      a[2 * p + 0] = fmaf(N2.x, __builtin_amdgcn_rcpf(D2.x), s0);
      float s1 = N1.y * __builtin_amdgcn_rcpf(D1.y);
      a[2 * p + 1] = fmaf(N2.y, __builtin_amdgcn_rcpf(D2.y), s1);
    }
    // reduction tree: DPP for levels 1,2 (value-halving) + 4,8 (row sums);
    // DS only for xor16/xor32. Lane l<4 ends with q=l (R13-verified layout).
    {
      const bool h1 = lane & 1;
      float m0 = h1 ? a[1] : a[0], o0 = h1 ? a[0] : a[1];
      float m1 = h1 ? a[3] : a[2], o1 = h1 ? a[2] : a[3];
      float r0 = m0 + dpp_mov<0xB1>(o0);    // quad_perm [1,0,3,2] == xor1
      float r1 = m1 + dpp_mov<0xB1>(o1);
      const bool h2 = lane & 2;
      float mm = h2 ? r1 : r0, oo = h2 ? r0 : r1;
      float r = mm + dpp_mov<0x4E>(oo);     // quad_perm [2,3,0,1] == xor2
      r += dpp_mov<0x124>(r);               // row_ror:4  (sum quads)
      r += dpp_mov<0x128>(r);               // row_ror:8
      r += __shfl_xor(r, 16, 64);
      r += __shfl_xor(r, 32, 64);
      if (lane < QT) s_sc[lane][t] = r;     // -2 already folded into v
    }
  }
  __syncthreads();

  // ---- softmax: waves 0..3 handle row = wave; waves 4..7 wait ----
  if (wave < QT) {
    const int r = wave;
    float x[4];
    #pragma unroll
    for (int i = 0; i < 4; ++i) x[i] = s_sc[r][lane + 64 * i];
    float m = fmaxf(fmaxf(x[0], x[1]), fmaxf(x[2], x[3]));
    #pragma unroll
    for (int off = 32; off >= 1; off >>= 1) m = fmaxf(m, __shfl_xor(m, off, 64));
    const float L2E = 1.4426950408889634f;
    float ssum = 0.f;
    #pragma unroll
    for (int i = 0; i < 4; ++i) { x[i] = __builtin_amdgcn_exp2f((x[i] - m) * L2E); ssum += x[i]; }
    #pragma unroll
    for (int off = 32; off >= 1; off >>= 1) ssum += __shfl_xor(ssum, off, 64);
    float inv = 1.f / ssum;
    float* oe = out_e + (size_t)(b * TD + q0 + r) * TE;
    #pragma unroll
    for (int i = 0; i < 4; ++i) {
      float e = x[i] * inv;
      s_sc[r][lane + 64 * i] = e;
      oe[lane + 64 * i] = e;
    }
  }
  __syncthreads();

  // ---- context: c[q][f4..f4+3] = sum_t e[q][t]*enc[b][t][f4..f4+3] ----
  {
    const int fgrp = tid >> 7;           // 0..3
    const int f4   = (tid & 127) * 4;
    float4 c[QT];
    #pragma unroll
    for (int q = 0; q < QT; ++q) c[q] = make_float4(0.f, 0.f, 0.f, 0.f);
    const float* eb = enc + (size_t)b * TE * DE + f4;
    const int tb = fgrp * 64;
    #pragma unroll 4
    for (int t = tb; t < tb + 64; ++t) {
      float4 ee = *(const float4*)(eb + (size_t)t * DE);
      #pragma unroll
      for (int q = 0; q < QT; ++q) {
        float w = s_sc[q][t];
        c[q].x = fmaf(w, ee.x, c[q].x);
        c[q].y = fmaf(w, ee.y, c[q].y);
        c[q].z = fmaf(w, ee.z, c[q].z);
        c[q].w = fmaf(w, ee.w, c[q].w);
      }
    }
    if (fgrp > 0) {
      #pragma unroll
      for (int q = 0; q < QT; ++q) *(float4*)&red[fgrp - 1][q][f4] = c[q];
    }
    __syncthreads();
    if (fgrp == 0) {
      #pragma unroll
      for (int q = 0; q < QT; ++q) {
        float4 r1 = *(const float4*)&red[0][q][f4];
        float4 r2 = *(const float4*)&red[1][q][f4];
        float4 r3 = *(const float4*)&red[2][q][f4];
        c[q].x += (r1.x + r2.x) + r3.x;
        c[q].y += (r1.y + r2.y) + r3.y;
        c[q].z += (r1.z + r2.z) + r3.z;
        c[q].w += (r1.w + r2.w) + r3.w;
        *(float4*)(out_c + (size_t)(b * TD + q0 + q) * DE + f4) = c[q];
      }
    }
  }
}

extern "C" void kernel_launch(void* const* d_in, const int* in_sizes, int n_in,
                              void* d_out, int out_size, void* d_ws, size_t ws_size,
                              hipStream_t stream) {
  const float* enc = (const float*)d_in[0];
  const float* dec = (const float*)d_in[1];
  const float* Wa  = (const float*)d_in[2];
  const float* Ua  = (const float*)d_in[3];
  const float* Va  = (const float*)d_in[4];
  float* out_c = (float*)d_out;
  float* out_e = out_c + (size_t)NB * TD * DE;          // c first, then e

  // workspace layout (10 MB):
  float* ws = (float*)d_ws;                             // ew = e^{2Ws}: 4 MB
  float* uh = ws + 1048576;                             // eu = e^{2Uh}: 4 MB
  unsigned short* BHw = (unsigned short*)(uh + 1048576);// 0.5 MB each
  unsigned short* BLw = BHw + 262144;
  unsigned short* BHu = BLw + 262144;
  unsigned short* BLu = BHu + 262144;

  convB<<<dim3(16, 16, 2), dim3(256), 0, stream>>>(Wa, BHw, BLw, Ua, BHu, BLu);
  gemm_mfma<<<dim3(8, 32, 2), dim3(256), 0, stream>>>(
      enc, BHw, BLw, ws, dec, BHu, BLu, uh);
  attn<<<dim3(NB * (TD / QT)), dim3(512), 0, stream>>>(
      ws, uh, enc, Va, out_c, out_e);
}